// Round 10
// baseline (105.076 us; speedup 1.0000x reference)
//
#include <hip/hip_runtime.h>

// SVF cascade frequency response on MI355X (gfx950) — R9.
//
// H(x) = (1+1j) * prod_k (b0*x^2+b1*x+b2)/(a0*x^2+a1*x+a2)
//
// Established: PLANAR output [Re H | Im H]; np ref is f32-computed (3.8e-6
// residue is the ref's noise); f64 internal compute, per-stage division,
// quartic pair-fusion with powers x..x^4 (R7/R8, absmax bit-stable).
//
// R9 theory: VALUBusy pinned ~66% across R6-R8 regardless of occupancy ->
// the single per-CU LDS unit is co-saturated: 32 waves x 10 ds_read_b64 x
// ~6cyc = 1920 LDS cycles/stage/CU == VALU cycles/stage/SIMD. Fix: deliver
// wave-uniform coefficients through the SCALAR path instead. A pre-kernel
// writes the 32x10 quartic coefs to d_ws; the main kernel reads them with a
// loop-uniform index -> s_load into SGPRs (scalar pipe + constant cache),
// zero LDS, no __syncthreads. Per-sample arithmetic BIT-IDENTICAL to R8.

#define NSEC  64
#define NPAIR 32
#define BLOCK 256
#define MPT   2    // samples per thread

__device__ __forceinline__ double rcp_f64_n1(double a) {
    double y = __builtin_amdgcn_rcp(a);        // v_rcp_f64, ~1e-8 rel
    y = fma(fma(-a, y, 1.0), y, y);            // 1 Newton -> ~1e-16 (~1 ulp)
    return y;
}

// Pre-kernel: compute quartic (pair-fused) coefficients into d_ws.
// Layout: coef[p*10 + 0..4] = num c0..c4, coef[p*10 + 5..9] = den c0..c4.
__global__ __launch_bounds__(64) void svf_coef_v9(
    const float* __restrict__ f_g,  const float* __restrict__ R_g,
    const float* __restrict__ lp_g, const float* __restrict__ bp_g,
    const float* __restrict__ hp_g,
    double* __restrict__ coef)
{
    const int t = threadIdx.x;
    if (t >= NPAIR) return;
    const int k0 = 2 * t, k1 = 2 * t + 1;
    double fk = (double)f_g[k0],  Rk = (double)R_g[k0];
    double lp = (double)lp_g[k0], bp = (double)bp_g[k0], hp = (double)hp_g[k0];
    double f2 = fk * fk, fbp = fk * bp, flp = f2 * lp, rf2 = 2.0 * Rk * fk;
    const double b0 = flp + fbp + hp, b1 = 2.0 * flp - 2.0 * hp, b2 = flp - fbp + hp;
    const double a0 = f2 + rf2 + 1.0, a1 = 2.0 * f2 - 2.0,       a2 = f2 - rf2 + 1.0;
    fk = (double)f_g[k1];  Rk = (double)R_g[k1];
    lp = (double)lp_g[k1]; bp = (double)bp_g[k1]; hp = (double)hp_g[k1];
    f2 = fk * fk; fbp = fk * bp; flp = f2 * lp; rf2 = 2.0 * Rk * fk;
    const double B0 = flp + fbp + hp, B1 = 2.0 * flp - 2.0 * hp, B2 = flp - fbp + hp;
    const double A0 = f2 + rf2 + 1.0, A1 = 2.0 * f2 - 2.0,       A2 = f2 - rf2 + 1.0;
    double* cp = coef + t * 10;
    cp[0] = b0 * B0;
    cp[1] = b0 * B1 + b1 * B0;
    cp[2] = b0 * B2 + b1 * B1 + b2 * B0;
    cp[3] = b1 * B2 + b2 * B1;
    cp[4] = b2 * B2;
    cp[5] = a0 * A0;
    cp[6] = a0 * A1 + a1 * A0;
    cp[7] = a0 * A2 + a1 * A1 + a2 * A0;
    cp[8] = a1 * A2 + a2 * A1;
    cp[9] = a2 * A2;
}

__global__ __launch_bounds__(BLOCK) void svf_f64_v9(
    const float* __restrict__ xr_g, const float* __restrict__ xi_g,
    const double* __restrict__ coef,
    float* __restrict__ out, int n, long long cap_floats)
{
    const int t = threadIdx.x;
    const long long base = (long long)(blockIdx.x * BLOCK + t) * MPT;

    double Xr[MPT], Xi[MPT];
    double X2r[MPT], X2i[MPT], X3r[MPT], X3i[MPT], X4r[MPT], X4i[MPT];
    double Hr[MPT], Hi[MPT];

    if (base + MPT <= (long long)n) {
        const float2 a = *reinterpret_cast<const float2*>(xr_g + base);
        const float2 b = *reinterpret_cast<const float2*>(xi_g + base);
        Xr[0] = (double)a.x; Xr[1] = (double)a.y;
        Xi[0] = (double)b.x; Xi[1] = (double)b.y;
    } else {
        for (int m = 0; m < MPT; ++m) {
            const long long idx = base + m;
            const bool ok = idx < (long long)n;
            Xr[m] = ok ? (double)xr_g[idx] : 1.0;
            Xi[m] = ok ? (double)xi_g[idx] : 0.0;
        }
    }

    #pragma unroll
    for (int m = 0; m < MPT; ++m) {
        X2r[m] = fma(Xr[m],  Xr[m],  -(Xi[m]  * Xi[m]));   // x^2
        X2i[m] = 2.0 * Xr[m] * Xi[m];
        X3r[m] = fma(X2r[m], Xr[m],  -(X2i[m] * Xi[m]));   // x^3
        X3i[m] = fma(X2r[m], Xi[m],    X2i[m] * Xr[m]);
        X4r[m] = fma(X2r[m], X2r[m], -(X2i[m] * X2i[m]));  // x^4
        X4i[m] = 2.0 * X2r[m] * X2i[m];
        Hr[m] = 1.0;   // H starts at (1 + 1j)
        Hi[m] = 1.0;
    }

    #pragma unroll 2
    for (int p = 0; p < NPAIR; ++p) {
        // Loop-uniform index -> scalar loads (s_load), no LDS, no VALU cost.
        const double* cp = coef + p * 10;
        const double c0 = cp[0], c1 = cp[1], c2 = cp[2], c3 = cp[3], c4 = cp[4];
        const double d0 = cp[5], d1 = cp[6], d2c = cp[7], d3 = cp[8], d4 = cp[9];
        #pragma unroll
        for (int m = 0; m < MPT; ++m) {
            // num quartic (real coefs, complex powers precomputed)
            const double nr = fma(c0, X4r[m], fma(c1, X3r[m],
                               fma(c2, X2r[m], fma(c3, Xr[m], c4))));
            const double ni = fma(c0, X4i[m], fma(c1, X3i[m],
                               fma(c2, X2i[m], c3 * Xi[m])));
            // den quartic
            const double dr = fma(d0, X4r[m], fma(d1, X3r[m],
                               fma(d2c, X2r[m], fma(d3, Xr[m], d4))));
            const double di = fma(d0, X4i[m], fma(d1, X3i[m],
                               fma(d2c, X2i[m], d3 * Xi[m])));
            // ratio = num * conj(den) / |den|^2 (per-stage division)
            const double dd  = fma(dr, dr, di * di);
            const double inv = rcp_f64_n1(dd);
            const double rr  = fma(nr, dr,   ni * di) * inv;
            const double ri  = fma(ni, dr, -(nr * di)) * inv;
            // H *= ratio
            const double hr = fma(Hr[m], rr, -(Hi[m] * ri));
            const double hi = fma(Hr[m], ri,   Hi[m] * rr);
            Hr[m] = hr; Hi[m] = hi;
        }
    }

    // PLANAR output: out[0..n-1] = Re H, out[n..2n-1] = Im H.
    // Single f64->f32 rounding; every store guarded by cap_floats.
    const long long imag_off = (long long)n;
    if (base + MPT <= (long long)n && 2LL * (long long)n <= cap_floats) {
        float2 vr, vi;
        vr.x = (float)Hr[0]; vr.y = (float)Hr[1];
        vi.x = (float)Hi[0]; vi.y = (float)Hi[1];
        *reinterpret_cast<float2*>(out + base)            = vr;
        *reinterpret_cast<float2*>(out + imag_off + base) = vi;
    } else {
        for (int m = 0; m < MPT; ++m) {
            const long long idx = base + m;
            if (idx < (long long)n) {
                if (idx + 1 <= cap_floats) out[idx] = (float)Hr[m];
                const long long oi = imag_off + idx;
                if (oi + 1 <= cap_floats) out[oi] = (float)Hi[m];
            }
        }
    }
}

extern "C" void kernel_launch(void* const* d_in, const int* in_sizes, int n_in,
                              void* d_out, int out_size, void* d_ws, size_t ws_size,
                              hipStream_t stream) {
    const float* xr = (const float*)d_in[0];
    const float* xi = (const float*)d_in[1];
    const float* f  = (const float*)d_in[2];
    const float* R  = (const float*)d_in[3];
    const float* lp = (const float*)d_in[4];
    const float* bp = (const float*)d_in[5];
    const float* hp = (const float*)d_in[6];
    float* out = (float*)d_out;
    double* coef = (double*)d_ws;   // 32*10*8 = 2560 B of scratch

    const int n = in_sizes[0];  // 1048576
    long long cap = (long long)out_size;
    if (cap > 2LL * (long long)n) cap = 2LL * (long long)n;

    // Stage 1: coefficients into workspace (re-done every call; d_ws is
    // re-poisoned before each timed launch).
    svf_coef_v9<<<1, 64, 0, stream>>>(f, R, lp, bp, hp, coef);
    // Stage 2: main sweep. Same-stream ordering guarantees coef visibility.
    const int grid = (n + BLOCK * MPT - 1) / (BLOCK * MPT);  // 2048
    svf_f64_v9<<<grid, BLOCK, 0, stream>>>(xr, xi, coef, out, n, cap);
}

// Round 11
// 89.044 us; speedup vs baseline: 1.1800x; 1.1800x over previous
//
#include <hip/hip_runtime.h>

// SVF cascade frequency response on MI355X (gfx950) — R10.
//
// H(x) = (1+1j) * prod_k (b0*x^2+b1*x+b2)/(a0*x^2+a1*x+a2)
//
// Established: PLANAR output [Re H | Im H]; per-stage division; quartic
// pair-fusion with powers x..x^4; scalar-path coefficient delivery via
// d_ws (R9: LDS=0). R6-R9 f64 absmax 3.814697e-6 == the f32-computed np
// reference's own deviation from truth -> this dataset is empirically
// well-conditioned for f32. R10 switches the whole datapath to f32:
// f32 FMA issues 2cyc/wave (f64: 4) -> op floor ~12.5 us vs f64's ~25.
// Coefs still computed in f64 (pre-kernel), rounded once to f32.
// Division: v_rcp_f32 + 1 Newton (~1 ulp). Predicted dispatch ~20-25 us,
// absmax ~1e-5 vs 1.074e-4 threshold.

#define NSEC  64
#define NPAIR 32
#define BLOCK 256
#define MPT   2    // samples per thread

__device__ __forceinline__ float rcp_f32_n1(float a) {
    float y = __builtin_amdgcn_rcpf(a);          // v_rcp_f32, ~1e-7 rel
    y = fmaf(fmaf(-a, y, 1.0f), y, y);           // 1 Newton -> ~1 ulp
    return y;
}

// Pre-kernel: quartic (pair-fused) coefficients, computed in f64 for
// exactness, stored as f32 in d_ws.
// Layout: coef[p*10 + 0..4] = num c0..c4, coef[p*10 + 5..9] = den c0..c4.
__global__ __launch_bounds__(64) void svf_coef_v10(
    const float* __restrict__ f_g,  const float* __restrict__ R_g,
    const float* __restrict__ lp_g, const float* __restrict__ bp_g,
    const float* __restrict__ hp_g,
    float* __restrict__ coef)
{
    const int t = threadIdx.x;
    if (t >= NPAIR) return;
    const int k0 = 2 * t, k1 = 2 * t + 1;
    double fk = (double)f_g[k0],  Rk = (double)R_g[k0];
    double lp = (double)lp_g[k0], bp = (double)bp_g[k0], hp = (double)hp_g[k0];
    double f2 = fk * fk, fbp = fk * bp, flp = f2 * lp, rf2 = 2.0 * Rk * fk;
    const double b0 = flp + fbp + hp, b1 = 2.0 * flp - 2.0 * hp, b2 = flp - fbp + hp;
    const double a0 = f2 + rf2 + 1.0, a1 = 2.0 * f2 - 2.0,       a2 = f2 - rf2 + 1.0;
    fk = (double)f_g[k1];  Rk = (double)R_g[k1];
    lp = (double)lp_g[k1]; bp = (double)bp_g[k1]; hp = (double)hp_g[k1];
    f2 = fk * fk; fbp = fk * bp; flp = f2 * lp; rf2 = 2.0 * Rk * fk;
    const double B0 = flp + fbp + hp, B1 = 2.0 * flp - 2.0 * hp, B2 = flp - fbp + hp;
    const double A0 = f2 + rf2 + 1.0, A1 = 2.0 * f2 - 2.0,       A2 = f2 - rf2 + 1.0;
    float* cp = coef + t * 10;
    cp[0] = (float)(b0 * B0);
    cp[1] = (float)(b0 * B1 + b1 * B0);
    cp[2] = (float)(b0 * B2 + b1 * B1 + b2 * B0);
    cp[3] = (float)(b1 * B2 + b2 * B1);
    cp[4] = (float)(b2 * B2);
    cp[5] = (float)(a0 * A0);
    cp[6] = (float)(a0 * A1 + a1 * A0);
    cp[7] = (float)(a0 * A2 + a1 * A1 + a2 * A0);
    cp[8] = (float)(a1 * A2 + a2 * A1);
    cp[9] = (float)(a2 * A2);
}

__global__ __launch_bounds__(BLOCK) void svf_f32_v10(
    const float* __restrict__ xr_g, const float* __restrict__ xi_g,
    const float* __restrict__ coef,
    float* __restrict__ out, int n, long long cap_floats)
{
    const int t = threadIdx.x;
    const long long base = (long long)(blockIdx.x * BLOCK + t) * MPT;

    float Xr[MPT], Xi[MPT];
    float X2r[MPT], X2i[MPT], X3r[MPT], X3i[MPT], X4r[MPT], X4i[MPT];
    float Hr[MPT], Hi[MPT];

    if (base + MPT <= (long long)n) {
        const float2 a = *reinterpret_cast<const float2*>(xr_g + base);
        const float2 b = *reinterpret_cast<const float2*>(xi_g + base);
        Xr[0] = a.x; Xr[1] = a.y;
        Xi[0] = b.x; Xi[1] = b.y;
    } else {
        for (int m = 0; m < MPT; ++m) {
            const long long idx = base + m;
            const bool ok = idx < (long long)n;
            Xr[m] = ok ? xr_g[idx] : 1.0f;
            Xi[m] = ok ? xi_g[idx] : 0.0f;
        }
    }

    #pragma unroll
    for (int m = 0; m < MPT; ++m) {
        X2r[m] = fmaf(Xr[m],  Xr[m],  -(Xi[m]  * Xi[m]));   // x^2
        X2i[m] = 2.0f * Xr[m] * Xi[m];
        X3r[m] = fmaf(X2r[m], Xr[m],  -(X2i[m] * Xi[m]));   // x^3
        X3i[m] = fmaf(X2r[m], Xi[m],    X2i[m] * Xr[m]);
        X4r[m] = fmaf(X2r[m], X2r[m], -(X2i[m] * X2i[m]));  // x^4
        X4i[m] = 2.0f * X2r[m] * X2i[m];
        Hr[m] = 1.0f;   // H starts at (1 + 1j)
        Hi[m] = 1.0f;
    }

    #pragma unroll 2
    for (int p = 0; p < NPAIR; ++p) {
        // Loop-uniform index -> scalar loads (s_load), no LDS, no VALU cost.
        const float* cp = coef + p * 10;
        const float c0 = cp[0], c1 = cp[1], c2 = cp[2], c3 = cp[3], c4 = cp[4];
        const float d0 = cp[5], d1 = cp[6], d2c = cp[7], d3 = cp[8], d4 = cp[9];
        #pragma unroll
        for (int m = 0; m < MPT; ++m) {
            // num quartic (real coefs, complex powers precomputed)
            const float nr = fmaf(c0, X4r[m], fmaf(c1, X3r[m],
                              fmaf(c2, X2r[m], fmaf(c3, Xr[m], c4))));
            const float ni = fmaf(c0, X4i[m], fmaf(c1, X3i[m],
                              fmaf(c2, X2i[m], c3 * Xi[m])));
            // den quartic
            const float dr = fmaf(d0, X4r[m], fmaf(d1, X3r[m],
                              fmaf(d2c, X2r[m], fmaf(d3, Xr[m], d4))));
            const float di = fmaf(d0, X4i[m], fmaf(d1, X3i[m],
                              fmaf(d2c, X2i[m], d3 * Xi[m])));
            // ratio = num * conj(den) / |den|^2 (per-stage division)
            const float dd  = fmaf(dr, dr, di * di);
            const float inv = rcp_f32_n1(dd);
            const float rr  = fmaf(nr, dr,   ni * di) * inv;
            const float ri  = fmaf(ni, dr, -(nr * di)) * inv;
            // H *= ratio
            const float hr = fmaf(Hr[m], rr, -(Hi[m] * ri));
            const float hi = fmaf(Hr[m], ri,   Hi[m] * rr);
            Hr[m] = hr; Hi[m] = hi;
        }
    }

    // PLANAR output: out[0..n-1] = Re H, out[n..2n-1] = Im H.
    // Every store guarded by cap_floats.
    const long long imag_off = (long long)n;
    if (base + MPT <= (long long)n && 2LL * (long long)n <= cap_floats) {
        float2 vr, vi;
        vr.x = Hr[0]; vr.y = Hr[1];
        vi.x = Hi[0]; vi.y = Hi[1];
        *reinterpret_cast<float2*>(out + base)            = vr;
        *reinterpret_cast<float2*>(out + imag_off + base) = vi;
    } else {
        for (int m = 0; m < MPT; ++m) {
            const long long idx = base + m;
            if (idx < (long long)n) {
                if (idx + 1 <= cap_floats) out[idx] = Hr[m];
                const long long oi = imag_off + idx;
                if (oi + 1 <= cap_floats) out[oi] = Hi[m];
            }
        }
    }
}

extern "C" void kernel_launch(void* const* d_in, const int* in_sizes, int n_in,
                              void* d_out, int out_size, void* d_ws, size_t ws_size,
                              hipStream_t stream) {
    const float* xr = (const float*)d_in[0];
    const float* xi = (const float*)d_in[1];
    const float* f  = (const float*)d_in[2];
    const float* R  = (const float*)d_in[3];
    const float* lp = (const float*)d_in[4];
    const float* bp = (const float*)d_in[5];
    const float* hp = (const float*)d_in[6];
    float* out = (float*)d_out;
    float* coef = (float*)d_ws;   // 32*10*4 = 1280 B of scratch

    const int n = in_sizes[0];  // 1048576
    long long cap = (long long)out_size;
    if (cap > 2LL * (long long)n) cap = 2LL * (long long)n;

    // Stage 1: coefficients (f64 math, f32 store) into workspace.
    svf_coef_v10<<<1, 64, 0, stream>>>(f, R, lp, bp, hp, coef);
    // Stage 2: main sweep, all-f32 datapath.
    const int grid = (n + BLOCK * MPT - 1) / (BLOCK * MPT);  // 2048
    svf_f32_v10<<<grid, BLOCK, 0, stream>>>(xr, xi, coef, out, n, cap);
}

// Round 12
// 82.336 us; speedup vs baseline: 1.2762x; 1.0815x over previous
//
#include <hip/hip_runtime.h>

// SVF cascade frequency response on MI355X (gfx950) — R11.
//
// H(x) = (1+1j) * prod_k (b0*x^2+b1*x+b2)/(a0*x^2+a1*x+a2)
//
// Established: PLANAR output [Re H | Im H]; f32 datapath passes with the
// same absmax (3.81e-6) as f64 -> residue is the f32-computed np ref's own
// noise; per-stage division (never reopen deferred); scalar-path coef
// delivery via d_ws; all stores guarded (abort superstition, free).
//
// R11: OCTIC fusion — 4 sections per stage, 16 stages of degree-8
// real-coefficient rationals. Powers x..x^8 precomputed per sample; poly
// cost stays 2 ops/degree but the 13-op stage overhead is paid 16x not 32x
// (~970 -> ~750 ops/sample). rcp Newton dropped (1e-7 rel x 16 -> ~1e-8
// abs). Stage loop fully unrolled so s_loads pipeline across stages.
// Coefs computed in f64 pre-kernel, rounded once to f32 (16*18 = 288 f32
// = 1152 B in d_ws).

#define NSEC  64
#define NOCT  16
#define BLOCK 256
#define MPT   2    // samples per thread

// Pre-kernel: octic (4-section fused) coefficients in f64, stored f32.
// Layout: coef[t*18 + 0..8] = num e0..e8 (x^8..x^0), [9..17] = den e0..e8.
__global__ __launch_bounds__(64) void svf_coef_v11(
    const float* __restrict__ f_g,  const float* __restrict__ R_g,
    const float* __restrict__ lp_g, const float* __restrict__ bp_g,
    const float* __restrict__ hp_g,
    float* __restrict__ coef)
{
    const int t = threadIdx.x;
    if (t >= NOCT) return;

    double qn[2][5], qd[2][5];   // two quartics (pairs of sections)
    for (int s = 0; s < 2; ++s) {
        const int k0 = 4 * t + 2 * s, k1 = k0 + 1;
        double fk = (double)f_g[k0],  Rk = (double)R_g[k0];
        double lp = (double)lp_g[k0], bp = (double)bp_g[k0], hp = (double)hp_g[k0];
        double f2 = fk * fk, fbp = fk * bp, flp = f2 * lp, rf2 = 2.0 * Rk * fk;
        const double b0 = flp + fbp + hp, b1 = 2.0 * flp - 2.0 * hp, b2 = flp - fbp + hp;
        const double a0 = f2 + rf2 + 1.0, a1 = 2.0 * f2 - 2.0,       a2 = f2 - rf2 + 1.0;
        fk = (double)f_g[k1];  Rk = (double)R_g[k1];
        lp = (double)lp_g[k1]; bp = (double)bp_g[k1]; hp = (double)hp_g[k1];
        f2 = fk * fk; fbp = fk * bp; flp = f2 * lp; rf2 = 2.0 * Rk * fk;
        const double B0 = flp + fbp + hp, B1 = 2.0 * flp - 2.0 * hp, B2 = flp - fbp + hp;
        const double A0 = f2 + rf2 + 1.0, A1 = 2.0 * f2 - 2.0,       A2 = f2 - rf2 + 1.0;
        qn[s][0] = b0 * B0;
        qn[s][1] = b0 * B1 + b1 * B0;
        qn[s][2] = b0 * B2 + b1 * B1 + b2 * B0;
        qn[s][3] = b1 * B2 + b2 * B1;
        qn[s][4] = b2 * B2;
        qd[s][0] = a0 * A0;
        qd[s][1] = a0 * A1 + a1 * A0;
        qd[s][2] = a0 * A2 + a1 * A1 + a2 * A0;
        qd[s][3] = a1 * A2 + a2 * A1;
        qd[s][4] = a2 * A2;
    }
    // octic = quartic (x) quartic, degree 8 -> 9 coefficients
    double en[9], ed[9];
    for (int j = 0; j < 9; ++j) { en[j] = 0.0; ed[j] = 0.0; }
    for (int i = 0; i < 5; ++i)
        for (int j = 0; j < 5; ++j) {
            en[i + j] += qn[0][i] * qn[1][j];
            ed[i + j] += qd[0][i] * qd[1][j];
        }
    float* cp = coef + t * 18;
    for (int j = 0; j < 9; ++j) {
        cp[j]     = (float)en[j];
        cp[9 + j] = (float)ed[j];
    }
}

__global__ __launch_bounds__(BLOCK) void svf_f32_v11(
    const float* __restrict__ xr_g, const float* __restrict__ xi_g,
    const float* __restrict__ coef,
    float* __restrict__ out, int n, long long cap_floats)
{
    const int t = threadIdx.x;
    const long long base = (long long)(blockIdx.x * BLOCK + t) * MPT;

    float X1r[MPT], X1i[MPT], X2r[MPT], X2i[MPT], X3r[MPT], X3i[MPT];
    float X4r[MPT], X4i[MPT], X5r[MPT], X5i[MPT], X6r[MPT], X6i[MPT];
    float X7r[MPT], X7i[MPT], X8r[MPT], X8i[MPT];
    float Hr[MPT], Hi[MPT];

    if (base + MPT <= (long long)n) {
        const float2 a = *reinterpret_cast<const float2*>(xr_g + base);
        const float2 b = *reinterpret_cast<const float2*>(xi_g + base);
        X1r[0] = a.x; X1r[1] = a.y;
        X1i[0] = b.x; X1i[1] = b.y;
    } else {
        for (int m = 0; m < MPT; ++m) {
            const long long idx = base + m;
            const bool ok = idx < (long long)n;
            X1r[m] = ok ? xr_g[idx] : 1.0f;
            X1i[m] = ok ? xi_g[idx] : 0.0f;
        }
    }

    #pragma unroll
    for (int m = 0; m < MPT; ++m) {
        // powers x^2..x^8 via squarings/mults
        X2r[m] = fmaf(X1r[m], X1r[m], -(X1i[m] * X1i[m]));
        X2i[m] = 2.0f * X1r[m] * X1i[m];
        X3r[m] = fmaf(X2r[m], X1r[m], -(X2i[m] * X1i[m]));
        X3i[m] = fmaf(X2r[m], X1i[m],   X2i[m] * X1r[m]);
        X4r[m] = fmaf(X2r[m], X2r[m], -(X2i[m] * X2i[m]));
        X4i[m] = 2.0f * X2r[m] * X2i[m];
        X5r[m] = fmaf(X4r[m], X1r[m], -(X4i[m] * X1i[m]));
        X5i[m] = fmaf(X4r[m], X1i[m],   X4i[m] * X1r[m]);
        X6r[m] = fmaf(X3r[m], X3r[m], -(X3i[m] * X3i[m]));
        X6i[m] = 2.0f * X3r[m] * X3i[m];
        X7r[m] = fmaf(X4r[m], X3r[m], -(X4i[m] * X3i[m]));
        X7i[m] = fmaf(X4r[m], X3i[m],   X4i[m] * X3r[m]);
        X8r[m] = fmaf(X4r[m], X4r[m], -(X4i[m] * X4i[m]));
        X8i[m] = 2.0f * X4r[m] * X4i[m];
        Hr[m] = 1.0f;   // H starts at (1 + 1j)
        Hi[m] = 1.0f;
    }

    #pragma unroll
    for (int p = 0; p < NOCT; ++p) {
        // Loop-uniform -> s_load; full unroll lets the compiler pipeline
        // coefficient loads across stages.
        const float* cp = coef + p * 18;
        const float e0 = cp[0], e1 = cp[1], e2 = cp[2], e3 = cp[3], e4 = cp[4];
        const float e5 = cp[5], e6 = cp[6], e7 = cp[7], e8 = cp[8];
        const float g0 = cp[9], g1 = cp[10], g2 = cp[11], g3 = cp[12], g4 = cp[13];
        const float g5 = cp[14], g6 = cp[15], g7 = cp[16], g8 = cp[17];
        #pragma unroll
        for (int m = 0; m < MPT; ++m) {
            // num octic (real coefs, complex powers precomputed): 8+8 fma
            const float nr = fmaf(e0, X8r[m], fmaf(e1, X7r[m], fmaf(e2, X6r[m],
                             fmaf(e3, X5r[m], fmaf(e4, X4r[m], fmaf(e5, X3r[m],
                             fmaf(e6, X2r[m], fmaf(e7, X1r[m], e8))))))));
            const float ni = fmaf(e0, X8i[m], fmaf(e1, X7i[m], fmaf(e2, X6i[m],
                             fmaf(e3, X5i[m], fmaf(e4, X4i[m], fmaf(e5, X3i[m],
                             fmaf(e6, X2i[m], e7 * X1i[m])))))));
            // den octic
            const float dr = fmaf(g0, X8r[m], fmaf(g1, X7r[m], fmaf(g2, X6r[m],
                             fmaf(g3, X5r[m], fmaf(g4, X4r[m], fmaf(g5, X3r[m],
                             fmaf(g6, X2r[m], fmaf(g7, X1r[m], g8))))))));
            const float di = fmaf(g0, X8i[m], fmaf(g1, X7i[m], fmaf(g2, X6i[m],
                             fmaf(g3, X5i[m], fmaf(g4, X4i[m], fmaf(g5, X3i[m],
                             fmaf(g6, X2i[m], g7 * X1i[m])))))));
            // ratio = num * conj(den) / |den|^2 (per-stage division)
            const float dd  = fmaf(dr, dr, di * di);
            const float inv = __builtin_amdgcn_rcpf(dd);   // ~1e-7 rel, ok
            const float tr  = fmaf(nr, dr,   ni * di);
            const float ti  = fmaf(ni, dr, -(nr * di));
            const float rr  = tr * inv;
            const float ri  = ti * inv;
            // H *= ratio
            const float hr = fmaf(Hr[m], rr, -(Hi[m] * ri));
            const float hi = fmaf(Hr[m], ri,   Hi[m] * rr);
            Hr[m] = hr; Hi[m] = hi;
        }
    }

    // PLANAR output: out[0..n-1] = Re H, out[n..2n-1] = Im H. Guarded.
    const long long imag_off = (long long)n;
    if (base + MPT <= (long long)n && 2LL * (long long)n <= cap_floats) {
        float2 vr, vi;
        vr.x = Hr[0]; vr.y = Hr[1];
        vi.x = Hi[0]; vi.y = Hi[1];
        *reinterpret_cast<float2*>(out + base)            = vr;
        *reinterpret_cast<float2*>(out + imag_off + base) = vi;
    } else {
        for (int m = 0; m < MPT; ++m) {
            const long long idx = base + m;
            if (idx < (long long)n) {
                if (idx + 1 <= cap_floats) out[idx] = Hr[m];
                const long long oi = imag_off + idx;
                if (oi + 1 <= cap_floats) out[oi] = Hi[m];
            }
        }
    }
}

extern "C" void kernel_launch(void* const* d_in, const int* in_sizes, int n_in,
                              void* d_out, int out_size, void* d_ws, size_t ws_size,
                              hipStream_t stream) {
    const float* xr = (const float*)d_in[0];
    const float* xi = (const float*)d_in[1];
    const float* f  = (const float*)d_in[2];
    const float* R  = (const float*)d_in[3];
    const float* lp = (const float*)d_in[4];
    const float* bp = (const float*)d_in[5];
    const float* hp = (const float*)d_in[6];
    float* out = (float*)d_out;
    float* coef = (float*)d_ws;   // 16*18*4 = 1152 B of scratch

    const int n = in_sizes[0];  // 1048576
    long long cap = (long long)out_size;
    if (cap > 2LL * (long long)n) cap = 2LL * (long long)n;

    // Stage 1: octic coefficients (f64 math, f32 store) into workspace.
    svf_coef_v11<<<1, 64, 0, stream>>>(f, R, lp, bp, hp, coef);
    // Stage 2: main sweep, all-f32, 16 fully-unrolled octic stages.
    const int grid = (n + BLOCK * MPT - 1) / (BLOCK * MPT);  // 2048
    svf_f32_v11<<<grid, BLOCK, 0, stream>>>(xr, xi, coef, out, n, cap);
}